// Round 2
// baseline (710.895 us; speedup 1.0000x reference)
//
#include <hip/hip_runtime.h>

#define CC 128
#define NN 4096
#define NB 2
#define TQ 32
#define TK 64
#define KVS 68   // kvs LDS stride (pad: 4*cb+m banks, <=2-way)
#define PSS 36   // ps  LDS stride (pad: 4*m+q banks, <=2-way)

// ---------------- kernel A: q/k/v projections (1x1 conv) ----------------
// out[b][o][n] = sum_c W[o][c] * x[b][c][n]
__global__ __launch_bounds__(256) void qkv_proj(
    const float* __restrict__ x, const float* __restrict__ Wq,
    const float* __restrict__ Wk, const float* __restrict__ Wv,
    float* __restrict__ qo, float* __restrict__ ko, float* __restrict__ vo) {
  __shared__ float Ws[CC][KVS];   // W chunk: [o][kc..kc+63]
  __shared__ float xs[CC][32];    // x tile:  [c][n-32]
  const int t = threadIdx.x;
  const int n0 = blockIdx.x * 32;
  const int which = blockIdx.y;
  const int b = blockIdx.z;
  const float* W = (which == 0) ? Wq : (which == 1) ? Wk : Wv;
  float* out = (which == 0) ? qo : (which == 1) ? ko : vo;
  const float* xb = x + (size_t)b * CC * NN;

#pragma unroll
  for (int i = 0; i < 4; ++i) {           // stage x tile: 1024 float4
    int idx = t + 256 * i;
    int c = idx >> 3, n4 = (idx & 7) * 4;
    *(float4*)&xs[c][n4] = *(const float4*)&xb[(size_t)c * NN + n0 + n4];
  }
  const int rb = t >> 4;                  // owns rows rb + 16k (k=0..7)
  const int c2 = (t & 15) * 2;            // owns cols c2, c2+1
  float acc[8][2];
#pragma unroll
  for (int k8 = 0; k8 < 8; ++k8) { acc[k8][0] = 0.f; acc[k8][1] = 0.f; }

  for (int kc = 0; kc < CC; kc += 64) {
#pragma unroll
    for (int i = 0; i < 8; ++i) {         // stage W chunk: 2048 float4
      int idx = t + 256 * i;
      int o = idx >> 4, c4 = (idx & 15) * 4;
      *(float4*)&Ws[o][c4] = *(const float4*)&W[o * CC + kc + c4];
    }
    __syncthreads();
#pragma unroll 4
    for (int kk = 0; kk < 64; ++kk) {
      float2 xv = *(float2*)&xs[kc + kk][c2];
#pragma unroll
      for (int k8 = 0; k8 < 8; ++k8) {
        float w = Ws[rb + 16 * k8][kk];
        acc[k8][0] += w * xv.x;
        acc[k8][1] += w * xv.y;
      }
    }
    __syncthreads();
  }
#pragma unroll
  for (int k8 = 0; k8 < 8; ++k8) {
    size_t base = ((size_t)b * CC + rb + 16 * k8) * NN + n0 + c2;
    float2 r; r.x = acc[k8][0]; r.y = acc[k8][1];
    *(float2*)&out[base] = r;
  }
}

// ---------------- kernel B: flash attention (fp32) ----------------
// h[b][c][n] = sum_m v[b][c][m] * softmax_m(sum_c' q[b][c'][n] k[b][c'][m])
__global__ __launch_bounds__(256) void attn(
    const float* __restrict__ qg, const float* __restrict__ kg,
    const float* __restrict__ vg, float* __restrict__ hg) {
  __shared__ float qs[CC][TQ];        // 16 KB
  __shared__ float kvs[CC][KVS];      // 34.8 KB (K then V, two-phase)
  __shared__ float ps[TK][PSS];       // 9.2 KB  scores/probs [m][q]
  __shared__ float Ms[TQ], Ls[TQ], Al[TQ];
  const int t = threadIdx.x;
  const int b = blockIdx.y;
  const int n0 = blockIdx.x * TQ;
  const float* qb = qg + (size_t)b * CC * NN;
  const float* kb = kg + (size_t)b * CC * NN;
  const float* vb = vg + (size_t)b * CC * NN;

#pragma unroll
  for (int i = 0; i < 4; ++i) {         // stage Q tile: 1024 float4
    int idx = t + 256 * i;
    int c = idx >> 3, q4 = (idx & 7) * 4;
    *(float4*)&qs[c][q4] = *(const float4*)&qb[(size_t)c * NN + n0 + q4];
  }
  if (t < TQ) { Ms[t] = -1e30f; Ls[t] = 0.f; }

  const int sqi = (t & 15) * 2;         // score phase: q pair
  const int smi = (t >> 4) * 4;         // score phase: m quad
  const int q0  = (t >> 4) * 2;         // PV phase: q pair
  const int cb  = t & 15;               // PV phase: rows cb + 16k
  float O[16];
#pragma unroll
  for (int i = 0; i < 16; ++i) O[i] = 0.f;
  __syncthreads();

  for (int kt = 0; kt < NN / TK; ++kt) {
    const int m0 = kt * TK;
#pragma unroll
    for (int i = 0; i < 8; ++i) {       // stage K tile: 2048 float4
      int idx = t + 256 * i;
      int c = idx >> 4, m4 = (idx & 15) * 4;
      *(float4*)&kvs[c][m4] = *(const float4*)&kb[(size_t)c * NN + m0 + m4];
    }
    __syncthreads();                    // (1) K ready

    // scores: s[q][m] = sum_c qs[c][q]*kvs[c][m]   (2q x 4m per thread)
    float a00 = 0.f, a01 = 0.f, a02 = 0.f, a03 = 0.f;
    float a10 = 0.f, a11 = 0.f, a12 = 0.f, a13 = 0.f;
#pragma unroll 4
    for (int c = 0; c < CC; ++c) {
      float qv0 = qs[c][sqi], qv1 = qs[c][sqi + 1];
      float4 kv = *(float4*)&kvs[c][smi];
      a00 += qv0 * kv.x; a01 += qv0 * kv.y; a02 += qv0 * kv.z; a03 += qv0 * kv.w;
      a10 += qv1 * kv.x; a11 += qv1 * kv.y; a12 += qv1 * kv.z; a13 += qv1 * kv.w;
    }
    {
      float2 r;
      r.x = a00; r.y = a10; *(float2*)&ps[smi + 0][sqi] = r;
      r.x = a01; r.y = a11; *(float2*)&ps[smi + 1][sqi] = r;
      r.x = a02; r.y = a12; *(float2*)&ps[smi + 2][sqi] = r;
      r.x = a03; r.y = a13; *(float2*)&ps[smi + 3][sqi] = r;
    }
    __syncthreads();                    // (2) scores in ps; kvs free

#pragma unroll
    for (int i = 0; i < 8; ++i) {       // stage V tile into kvs
      int idx = t + 256 * i;
      int c = idx >> 4, m4 = (idx & 15) * 4;
      *(float4*)&kvs[c][m4] = *(const float4*)&vb[(size_t)c * NN + m0 + m4];
    }
    // online softmax: wave 0, lane = (q, half-of-m)
    if (t < 64) {
      const int q = t & 31, hlf = t >> 5, mb = hlf * 32;
      float tm = -1e30f;
#pragma unroll 8
      for (int mm = 0; mm < 32; ++mm) tm = fmaxf(tm, ps[mb + mm][q]);
      tm = fmaxf(tm, __shfl_xor(tm, 32));
      const float Mold = Ms[q];
      const float Mnew = fmaxf(Mold, tm);
      float s = 0.f;
#pragma unroll 8
      for (int mm = 0; mm < 32; ++mm) {
        float p = __expf(ps[mb + mm][q] - Mnew);
        ps[mb + mm][q] = p;
        s += p;
      }
      s += __shfl_xor(s, 32);
      if (hlf == 0) {
        float al = __expf(Mold - Mnew);
        Al[q] = al;
        Ls[q] = Ls[q] * al + s;
        Ms[q] = Mnew;
      }
    }
    __syncthreads();                    // (3) V + probs ready

    // PV: O[c][q] = O*alpha + sum_m v[c][m] p[m][q]   (8c x 2q per thread)
    const float al0 = Al[q0], al1 = Al[q0 + 1];
#pragma unroll
    for (int k = 0; k < 8; ++k) { O[k] *= al0; O[8 + k] *= al1; }
#pragma unroll 2
    for (int m4 = 0; m4 < TK; m4 += 4) {
      float2 p0 = *(float2*)&ps[m4 + 0][q0];
      float2 p1 = *(float2*)&ps[m4 + 1][q0];
      float2 p2 = *(float2*)&ps[m4 + 2][q0];
      float2 p3 = *(float2*)&ps[m4 + 3][q0];
#pragma unroll
      for (int k = 0; k < 8; ++k) {
        float4 vv = *(float4*)&kvs[cb + 16 * k][m4];
        O[k]     += vv.x * p0.x + vv.y * p1.x + vv.z * p2.x + vv.w * p3.x;
        O[8 + k] += vv.x * p0.y + vv.y * p1.y + vv.z * p2.y + vv.w * p3.y;
      }
    }
    __syncthreads();                    // (4) PV done; safe to overwrite kvs
  }

  const float li0 = 1.f / Ls[q0], li1 = 1.f / Ls[q0 + 1];
#pragma unroll
  for (int k = 0; k < 8; ++k) {
    int c = cb + 16 * k;
    size_t base = ((size_t)b * CC + c) * NN + n0 + q0;
    float2 r; r.x = O[k] * li0; r.y = O[8 + k] * li1;
    *(float2*)&hg[base] = r;
  }
}

// ---------------- kernel C: output projection + residual + GN stats ----------------
__global__ __launch_bounds__(256) void proj_o(
    const float* __restrict__ x, const float* __restrict__ Wo,
    const float* __restrict__ h, float* __restrict__ y, float* __restrict__ stats) {
  __shared__ float Ws[CC][KVS];
  __shared__ float hs[CC][32];
  __shared__ float gsum[8], gsq[8];
  const int t = threadIdx.x;
  const int n0 = blockIdx.x * 32;
  const int b = blockIdx.y;
  const float* hb = h + (size_t)b * CC * NN;

#pragma unroll
  for (int i = 0; i < 4; ++i) {
    int idx = t + 256 * i;
    int c = idx >> 3, n4 = (idx & 7) * 4;
    *(float4*)&hs[c][n4] = *(const float4*)&hb[(size_t)c * NN + n0 + n4];
  }
  if (t < 8) { gsum[t] = 0.f; gsq[t] = 0.f; }
  const int rb = t >> 4;
  const int c2 = (t & 15) * 2;
  float acc[8][2];
#pragma unroll
  for (int k8 = 0; k8 < 8; ++k8) { acc[k8][0] = 0.f; acc[k8][1] = 0.f; }

  for (int kc = 0; kc < CC; kc += 64) {
#pragma unroll
    for (int i = 0; i < 8; ++i) {
      int idx = t + 256 * i;
      int o = idx >> 4, c4 = (idx & 15) * 4;
      *(float4*)&Ws[o][c4] = *(const float4*)&Wo[o * CC + kc + c4];
    }
    __syncthreads();
#pragma unroll 4
    for (int kk = 0; kk < 64; ++kk) {
      float2 xv = *(float2*)&hs[kc + kk][c2];
#pragma unroll
      for (int k8 = 0; k8 < 8; ++k8) {
        float w = Ws[rb + 16 * k8][kk];
        acc[k8][0] += w * xv.x;
        acc[k8][1] += w * xv.y;
      }
    }
    __syncthreads();
  }
  // rows rb+16k are entirely inside group k (16 channels per group)
#pragma unroll
  for (int k8 = 0; k8 < 8; ++k8) {
    size_t base = ((size_t)b * CC + rb + 16 * k8) * NN + n0 + c2;
    float2 xv = *(const float2*)&x[base];
    float y0 = acc[k8][0] + xv.x;
    float y1 = acc[k8][1] + xv.y;
    float2 r; r.x = y0; r.y = y1;
    *(float2*)&y[base] = r;
    atomicAdd(&gsum[k8], y0 + y1);
    atomicAdd(&gsq[k8], y0 * y0 + y1 * y1);
  }
  __syncthreads();
  if (t < 8) {
    atomicAdd(&stats[(b * 8 + t) * 2 + 0], gsum[t]);
    atomicAdd(&stats[(b * 8 + t) * 2 + 1], gsq[t]);
  }
}

// ---------------- kernel D: GroupNorm finalize + affine + SiLU ----------------
__global__ __launch_bounds__(256) void gn_silu(
    const float* __restrict__ y, const float* __restrict__ stats,
    const float* __restrict__ gamma, const float* __restrict__ beta,
    float* __restrict__ out) {
  const int tid = blockIdx.x * 256 + threadIdx.x;
  const int i4 = tid * 4;
  const int c = (i4 >> 12) & (CC - 1);
  const int b = i4 >> 19;
  const int g = c >> 4;
  const float inv = 1.f / 65536.f;   // 16 channels * 4096 elems per group
  float sum = stats[(b * 8 + g) * 2 + 0];
  float sq  = stats[(b * 8 + g) * 2 + 1];
  float mean = sum * inv;
  float var = sq * inv - mean * mean;
  float rs = rsqrtf(var + 1e-5f);
  float ga = gamma[c], be = beta[c];
  float4 v4 = *(const float4*)&y[i4];
  float4 r;
  float o;
  o = (v4.x - mean) * rs * ga + be; r.x = o / (1.f + __expf(-o));
  o = (v4.y - mean) * rs * ga + be; r.y = o / (1.f + __expf(-o));
  o = (v4.z - mean) * rs * ga + be; r.z = o / (1.f + __expf(-o));
  o = (v4.w - mean) * rs * ga + be; r.w = o / (1.f + __expf(-o));
  *(float4*)&out[i4] = r;
}

__global__ void zero_stats(float* __restrict__ s) {
  if (threadIdx.x < 32) s[threadIdx.x] = 0.f;
}

extern "C" void kernel_launch(void* const* d_in, const int* in_sizes, int n_in,
                              void* d_out, int out_size, void* d_ws, size_t ws_size,
                              hipStream_t stream) {
  const float* x     = (const float*)d_in[0];
  const float* Wq    = (const float*)d_in[1];
  const float* Wk    = (const float*)d_in[2];
  const float* Wv    = (const float*)d_in[3];
  const float* Wo    = (const float*)d_in[4];
  const float* gamma = (const float*)d_in[5];
  const float* beta  = (const float*)d_in[6];
  float* out = (float*)d_out;
  float* ws  = (float*)d_ws;

  const size_t M = (size_t)NB * CC * NN;  // 1,048,576 elems per tensor
  float* q = ws;
  float* k = ws + M;
  float* v = ws + 2 * M;
  float* h = ws + 3 * M;
  float* y = ws;        // q buffer is dead after attn; reuse for y
  float* stats = k;     // k buffer is dead after attn; 32 floats, zeroed post-attn
                        // (total ws usage: exactly 4*M floats = 16 MiB — never
                        //  touch ws + 4*M; that overran d_ws in R1 and corrupted
                        //  the harness's pristine input copies)

  qkv_proj<<<dim3(NN / 32, 3, NB), 256, 0, stream>>>(x, Wq, Wk, Wv, q, k, v);
  attn<<<dim3(NN / TQ, NB), 256, 0, stream>>>(q, k, v, h);
  zero_stats<<<1, 64, 0, stream>>>(stats);
  proj_o<<<dim3(NN / 32, NB), 256, 0, stream>>>(x, Wo, h, y, stats);
  gn_silu<<<dim3((int)(M / 1024)), 256, 0, stream>>>(y, stats, gamma, beta, out);
}

// Round 3
// 298.750 us; speedup vs baseline: 2.3796x; 2.3796x over previous
//
#include <hip/hip_runtime.h>

#define CC 128
#define NN 4096
#define NB 2
#define TQ 32
#define TK 64

typedef unsigned short ushort;
typedef unsigned int uint;
typedef __attribute__((ext_vector_type(8))) short s8;    // 8 bf16 (4 VGPRs)
typedef __attribute__((ext_vector_type(4))) float f4;    // 4 fp32 acc
#define MFMA16(a, b, c) __builtin_amdgcn_mfma_f32_16x16x32_bf16(a, b, c, 0, 0, 0)

__device__ __forceinline__ ushort f2bf(float f) {
  uint u = __float_as_uint(f);
  u += 0x7fffu + ((u >> 16) & 1u);   // round-to-nearest-even
  return (ushort)(u >> 16);
}
__device__ __forceinline__ float wmax16(float v) {
  v = fmaxf(v, __shfl_xor(v, 1)); v = fmaxf(v, __shfl_xor(v, 2));
  v = fmaxf(v, __shfl_xor(v, 4)); v = fmaxf(v, __shfl_xor(v, 8));
  return v;
}
__device__ __forceinline__ float wsum16(float v) {
  v += __shfl_xor(v, 1); v += __shfl_xor(v, 2);
  v += __shfl_xor(v, 4); v += __shfl_xor(v, 8);
  return v;
}

// ---------------- kernel A: q/k/v projections -> bf16 ----------------
// q,k written TRANSPOSED [b][n][c] (for MFMA frag contiguity); v natural [b][c][n].
__global__ __launch_bounds__(256) void qkv_proj(
    const float* __restrict__ x, const float* __restrict__ Wq,
    const float* __restrict__ Wk, const float* __restrict__ Wv,
    ushort* __restrict__ qT, ushort* __restrict__ kT, ushort* __restrict__ vB) {
  __shared__ float Ws[CC][68];
  __shared__ float xs[CC][32];
  __shared__ ushort tr[32][136];
  const int t = threadIdx.x;
  const int n0 = blockIdx.x * 32;
  const int which = blockIdx.y;
  const int b = blockIdx.z;
  const float* W = (which == 0) ? Wq : (which == 1) ? Wk : Wv;
  const float* xb = x + (size_t)b * CC * NN;

#pragma unroll
  for (int i = 0; i < 4; ++i) {
    int idx = t + 256 * i;
    int c = idx >> 3, n4 = (idx & 7) * 4;
    *(float4*)&xs[c][n4] = *(const float4*)&xb[(size_t)c * NN + n0 + n4];
  }
  const int rb = t >> 4;
  const int c2 = (t & 15) * 2;
  float acc[8][2];
#pragma unroll
  for (int k8 = 0; k8 < 8; ++k8) { acc[k8][0] = 0.f; acc[k8][1] = 0.f; }

  for (int kc = 0; kc < CC; kc += 64) {
#pragma unroll
    for (int i = 0; i < 8; ++i) {
      int idx = t + 256 * i;
      int o = idx >> 4, c4 = (idx & 15) * 4;
      *(float4*)&Ws[o][c4] = *(const float4*)&W[o * CC + kc + c4];
    }
    __syncthreads();
#pragma unroll 4
    for (int kk = 0; kk < 64; ++kk) {
      float2 xv = *(float2*)&xs[kc + kk][c2];
#pragma unroll
      for (int k8 = 0; k8 < 8; ++k8) {
        float w = Ws[rb + 16 * k8][kk];
        acc[k8][0] += w * xv.x;
        acc[k8][1] += w * xv.y;
      }
    }
    __syncthreads();
  }

  if (which == 2) {                    // v: natural [b][c][n] bf16
#pragma unroll
    for (int k8 = 0; k8 < 8; ++k8) {
      int o = rb + 16 * k8;
      uint pk = (uint)f2bf(acc[k8][0]) | ((uint)f2bf(acc[k8][1]) << 16);
      ((uint*)vB)[(((size_t)b * CC + o) * NN + n0 + c2) >> 1] = pk;
    }
  } else {                             // q,k: transpose via LDS -> [b][n][c]
#pragma unroll
    for (int k8 = 0; k8 < 8; ++k8) {
      int o = rb + 16 * k8;
      tr[c2][o] = f2bf(acc[k8][0]);
      tr[c2 + 1][o] = f2bf(acc[k8][1]);
    }
    __syncthreads();
    ushort* out = (which == 0) ? qT : kT;
    int row = t >> 3, coff = (t & 7) * 16;
    size_t gb = ((size_t)b * NN + n0 + row) * CC + coff;
    *(int4*)&out[gb] = *(const int4*)&tr[row][coff];
    *(int4*)&out[gb + 8] = *(const int4*)&tr[row][coff + 8];
  }
}

// ---------------- kernel B: flash attention, bf16 MFMA ----------------
__global__ __launch_bounds__(256) void attn(
    const ushort* __restrict__ qTg, const ushort* __restrict__ kTg,
    const ushort* __restrict__ vBg, float* __restrict__ hg) {
  __shared__ ushort qsT[TQ][136];      // [n][c] +8 pad: b128 reads 2-way (free)
  __shared__ ushort ksT[TK][136];      // [m][c]
  __shared__ ushort vs[CC][72];        // [c][m]
  __shared__ ushort psb[TQ][72];       // [n][m] probs bf16
  __shared__ float Ms[TQ], Ls[TQ], Al[TQ];
  __shared__ float red_max[2][TQ], red_sum[2][TQ];

  const int t = threadIdx.x;
  const int b = blockIdx.y;
  const int n0 = blockIdx.x * TQ;
  const int w = t >> 6;                // wave 0..3
  const int lane = t & 63;
  const int quad = lane >> 4;
  const int l16 = lane & 15;
  const int nt = w >> 1, mh = w & 1;   // scores: n-tile, m-half
  const int ntb = nt * 16, mw = mh * 32;
  const int c0 = w * 32;               // PV: this wave's c-tiles [c0, c0+32)

  {  // stage Q tile (32 x 128 bf16)
    int row = t >> 3, coff = (t & 7) * 16;
    size_t gq = ((size_t)b * NN + n0 + row) * CC + coff;
    *(int4*)&qsT[row][coff] = *(const int4*)&qTg[gq];
    *(int4*)&qsT[row][coff + 8] = *(const int4*)&qTg[gq + 8];
  }
  if (t < TQ) { Ms[t] = -1e30f; Ls[t] = 0.f; }
  __syncthreads();

  s8 aq[4];                            // hoisted A-frags (Q constant over iters)
#pragma unroll
  for (int kk = 0; kk < 4; ++kk)
    aq[kk] = *(const s8*)&qsT[ntb + l16][kk * 32 + quad * 8];

  f4 o00 = {0.f, 0.f, 0.f, 0.f}, o01 = {0.f, 0.f, 0.f, 0.f};
  f4 o10 = {0.f, 0.f, 0.f, 0.f}, o11 = {0.f, 0.f, 0.f, 0.f};

  for (int kt = 0; kt < NN / TK; ++kt) {
    const int m0 = kt * TK;
#pragma unroll
    for (int i = 0; i < 4; ++i) {      // stage K^T tile (64 x 128)
      int ch = t + 256 * i;
      int rowk = ch >> 4, ck = (ch & 15) * 8;
      *(int4*)&ksT[rowk][ck] = *(const int4*)&kTg[((size_t)b * NN + m0 + rowk) * CC + ck];
    }
#pragma unroll
    for (int i = 0; i < 4; ++i) {      // stage V tile (128 x 64)
      int ch = t + 256 * i;
      int rowv = ch >> 3, mo = (ch & 7) * 8;
      *(int4*)&vs[rowv][mo] = *(const int4*)&vBg[((size_t)b * CC + rowv) * NN + m0 + mo];
    }
    __syncthreads();                   // (1) K,V ready

    // scores: wave computes S[ntb..+15][mw..+31] as two 16x16 tiles
    f4 s0 = {0.f, 0.f, 0.f, 0.f}, s1 = {0.f, 0.f, 0.f, 0.f};
#pragma unroll
    for (int kk = 0; kk < 4; ++kk) {
      s8 b0 = *(const s8*)&ksT[mw + l16][kk * 32 + quad * 8];
      s8 b1 = *(const s8*)&ksT[mw + 16 + l16][kk * 32 + quad * 8];
      s0 = MFMA16(aq[kk], b0, s0);
      s1 = MFMA16(aq[kk], b1, s1);
    }
    // wave-local row max over this m-half
#pragma unroll
    for (int r = 0; r < 4; ++r) {
      float rm = wmax16(fmaxf(s0[r], s1[r]));
      if (l16 == 0) red_max[mh][ntb + quad * 4 + r] = rm;
    }
    __syncthreads();                   // (2) row maxes visible

#pragma unroll
    for (int r = 0; r < 4; ++r) {      // exp + P(bf16) + partial row sums
      int row = ntb + quad * 4 + r;
      float Mn = fmaxf(Ms[row], fmaxf(red_max[0][row], red_max[1][row]));
      float p0 = __expf(s0[r] - Mn);
      float p1 = __expf(s1[r] - Mn);
      psb[row][mw + l16] = f2bf(p0);
      psb[row][mw + 16 + l16] = f2bf(p1);
      float ps = wsum16(p0 + p1);
      if (l16 == 0) red_sum[mh][row] = ps;
    }
    __syncthreads();                   // (3) P + sums visible

    if (mh == 0 && l16 == 0) {         // update running stats (one wave per n-tile)
#pragma unroll
      for (int r = 0; r < 4; ++r) {
        int row = ntb + quad * 4 + r;
        float Mold = Ms[row];
        float Mn = fmaxf(Mold, fmaxf(red_max[0][row], red_max[1][row]));
        float al = __expf(Mold - Mn);
        Ls[row] = Ls[row] * al + red_sum[0][row] + red_sum[1][row];
        Ms[row] = Mn;
        Al[row] = al;
      }
    }
    __syncthreads();                   // (4) alpha visible

    // PV: 4 persistent D-tiles per wave: (c0,c0+16) x (n-tile 0,1)
    const float al0 = Al[l16], al1 = Al[16 + l16];
    o00 *= al0; o01 *= al0; o10 *= al1; o11 *= al1;
#pragma unroll
    for (int mk = 0; mk < TK; mk += 32) {
      s8 a0 = *(const s8*)&vs[c0 + l16][mk + quad * 8];
      s8 a1 = *(const s8*)&vs[c0 + 16 + l16][mk + quad * 8];
      s8 pb0 = *(const s8*)&psb[l16][mk + quad * 8];
      s8 pb1 = *(const s8*)&psb[16 + l16][mk + quad * 8];
      o00 = MFMA16(a0, pb0, o00);
      o01 = MFMA16(a1, pb0, o01);
      o10 = MFMA16(a0, pb1, o10);
      o11 = MFMA16(a1, pb1, o11);
    }
    __syncthreads();                   // (5) PV done; kvs/psb reusable
  }

  const float li0 = 1.f / Ls[l16], li1 = 1.f / Ls[16 + l16];
#pragma unroll
  for (int r = 0; r < 4; ++r) {
    int ca = c0 + quad * 4 + r;
    int cb = c0 + 16 + quad * 4 + r;
    size_t ba = ((size_t)b * CC + ca) * NN + n0;
    size_t bb = ((size_t)b * CC + cb) * NN + n0;
    hg[ba + l16] = o00[r] * li0;
    hg[bb + l16] = o01[r] * li0;
    hg[ba + 16 + l16] = o10[r] * li1;
    hg[bb + 16 + l16] = o11[r] * li1;
  }
}

// ---------------- kernel C: output projection + residual + GN stats ----------------
__global__ __launch_bounds__(256) void proj_o(
    const float* __restrict__ x, const float* __restrict__ Wo,
    const float* __restrict__ h, float* __restrict__ y, float* __restrict__ stats) {
  __shared__ float Ws[CC][68];
  __shared__ float hs[CC][32];
  __shared__ float gsum[8], gsq[8];
  const int t = threadIdx.x;
  const int n0 = blockIdx.x * 32;
  const int b = blockIdx.y;
  const float* hb = h + (size_t)b * CC * NN;

#pragma unroll
  for (int i = 0; i < 4; ++i) {
    int idx = t + 256 * i;
    int c = idx >> 3, n4 = (idx & 7) * 4;
    *(float4*)&hs[c][n4] = *(const float4*)&hb[(size_t)c * NN + n0 + n4];
  }
  if (t < 8) { gsum[t] = 0.f; gsq[t] = 0.f; }
  const int rb = t >> 4;
  const int c2 = (t & 15) * 2;
  float acc[8][2];
#pragma unroll
  for (int k8 = 0; k8 < 8; ++k8) { acc[k8][0] = 0.f; acc[k8][1] = 0.f; }

  for (int kc = 0; kc < CC; kc += 64) {
#pragma unroll
    for (int i = 0; i < 8; ++i) {
      int idx = t + 256 * i;
      int o = idx >> 4, c4 = (idx & 15) * 4;
      *(float4*)&Ws[o][c4] = *(const float4*)&Wo[o * CC + kc + c4];
    }
    __syncthreads();
#pragma unroll 4
    for (int kk = 0; kk < 64; ++kk) {
      float2 xv = *(float2*)&hs[kc + kk][c2];
#pragma unroll
      for (int k8 = 0; k8 < 8; ++k8) {
        float w = Ws[rb + 16 * k8][kk];
        acc[k8][0] += w * xv.x;
        acc[k8][1] += w * xv.y;
      }
    }
    __syncthreads();
  }
#pragma unroll
  for (int k8 = 0; k8 < 8; ++k8) {
    size_t base = ((size_t)b * CC + rb + 16 * k8) * NN + n0 + c2;
    float2 xv = *(const float2*)&x[base];
    float y0 = acc[k8][0] + xv.x;
    float y1 = acc[k8][1] + xv.y;
    float2 r; r.x = y0; r.y = y1;
    *(float2*)&y[base] = r;
    atomicAdd(&gsum[k8], y0 + y1);
    atomicAdd(&gsq[k8], y0 * y0 + y1 * y1);
  }
  __syncthreads();
  if (t < 8) {
    atomicAdd(&stats[(b * 8 + t) * 2 + 0], gsum[t]);
    atomicAdd(&stats[(b * 8 + t) * 2 + 1], gsq[t]);
  }
}

// ---------------- kernel D: GroupNorm finalize + affine + SiLU ----------------
__global__ __launch_bounds__(256) void gn_silu(
    const float* __restrict__ y, const float* __restrict__ stats,
    const float* __restrict__ gamma, const float* __restrict__ beta,
    float* __restrict__ out) {
  const int tid = blockIdx.x * 256 + threadIdx.x;
  const int i4 = tid * 4;
  const int c = (i4 >> 12) & (CC - 1);
  const int b = i4 >> 19;
  const int g = c >> 4;
  const float inv = 1.f / 65536.f;
  float sum = stats[(b * 8 + g) * 2 + 0];
  float sq  = stats[(b * 8 + g) * 2 + 1];
  float mean = sum * inv;
  float var = sq * inv - mean * mean;
  float rs = rsqrtf(var + 1e-5f);
  float ga = gamma[c], be = beta[c];
  float4 v4 = *(const float4*)&y[i4];
  float4 r;
  float o;
  o = (v4.x - mean) * rs * ga + be; r.x = o / (1.f + __expf(-o));
  o = (v4.y - mean) * rs * ga + be; r.y = o / (1.f + __expf(-o));
  o = (v4.z - mean) * rs * ga + be; r.z = o / (1.f + __expf(-o));
  o = (v4.w - mean) * rs * ga + be; r.w = o / (1.f + __expf(-o));
  *(float4*)&out[i4] = r;
}

__global__ void zero_stats(float* __restrict__ s) {
  if (threadIdx.x < 32) s[threadIdx.x] = 0.f;
}

extern "C" void kernel_launch(void* const* d_in, const int* in_sizes, int n_in,
                              void* d_out, int out_size, void* d_ws, size_t ws_size,
                              hipStream_t stream) {
  const float* x     = (const float*)d_in[0];
  const float* Wq    = (const float*)d_in[1];
  const float* Wk    = (const float*)d_in[2];
  const float* Wv    = (const float*)d_in[3];
  const float* Wo    = (const float*)d_in[4];
  const float* gamma = (const float*)d_in[5];
  const float* beta  = (const float*)d_in[6];
  float* out = (float*)d_out;
  float* ws  = (float*)d_ws;

  // ws budget 16 MiB (R1 lesson: NEVER exceed — it corrupts harness state).
  // h 4MB | y 4MB | qT 2MB | kT 2MB | v 2MB | stats 128B   = 14 MB
  const size_t M = (size_t)NB * CC * NN;  // 1,048,576 elems
  float* h = ws;
  float* y = ws + M;
  ushort* qT = (ushort*)(ws + 2 * M);
  ushort* kT = qT + M;
  ushort* vB = kT + M;
  float* stats = (float*)(vB + M);

  zero_stats<<<1, 64, 0, stream>>>(stats);
  qkv_proj<<<dim3(NN / 32, 3, NB), 256, 0, stream>>>(x, Wq, Wk, Wv, qT, kT, vB);
  attn<<<dim3(NN / TQ, NB), 256, 0, stream>>>(qT, kT, vB, h);
  proj_o<<<dim3(NN / 32, NB), 256, 0, stream>>>(x, Wo, h, y, stats);
  gn_silu<<<dim3((int)(M / 1024)), 256, 0, stream>>>(y, stats, gamma, beta, out);
}